// Round 9
// baseline (271.668 us; speedup 1.0000x reference)
//
#include <hip/hip_runtime.h>
#include <hip/hip_bf16.h>
#include <stdint.h>

#define N_ATOMS 20000
#define NFEAT   2784
#define KP1     2816      // 44 * 64, K-pad for layer 1 (2784 real + 32 zero)
#define SS      500
#define NPAD    20224     // 158 * 128
#define MCOLS   1024      // P*H

typedef __attribute__((ext_vector_type(8))) short s16x8;
typedef __attribute__((ext_vector_type(4))) float f32x4;

static __device__ __forceinline__ unsigned short f2b(float f) {
    __hip_bfloat16 h = __float2bfloat16(f);
    return __builtin_bit_cast(unsigned short, h);
}
static __device__ __forceinline__ float b2f(unsigned short u) {
    unsigned int x = ((unsigned int)u) << 16;
    return __builtin_bit_cast(float, x);
}

#define GLOAD16(g, l) __builtin_amdgcn_global_load_lds( \
    (const __attribute__((address_space(1))) void*)(g), \
    (__attribute__((address_space(3))) void*)(l), 16, 0, 0)

// ---------------- Fused prep: conv_feat + pack_w(W1) + W2/W3/pw/zero ------------
// [R8-proven] blocks [0,20000): feat fp32->bf16; [20000,20352): pack W1;
// [20352,20496): pack W2 | pack W3 | make_pw | zero.
// LESSON (R2/R6/R7): fusing fp32->bf16 INTO gemm1's A-path failed 3 structural
// ways (latency-on-critical-path; regset spill 400MB; residual spill 80MB).
// Keep conversion as a separate BW-bound pass. Do not revisit.
__global__ void prep_all(const float* __restrict__ F, unsigned short* __restrict__ feat,
                         const float* __restrict__ W1, unsigned short* __restrict__ B1t,
                         const float* __restrict__ W2, const float* __restrict__ W3,
                         unsigned short* __restrict__ B2t, unsigned short* __restrict__ B3t,
                         const float* __restrict__ Wc, const int* __restrict__ spec,
                         float* __restrict__ pw, float* __restrict__ out) {
    __shared__ unsigned short tile[32][256];
    int b = blockIdx.x;
    int t = threadIdx.x;
    if (b < N_ATOMS) {
        const float4* src = (const float4*)(F + (size_t)b * NFEAT);
        unsigned short* dst = feat + (size_t)b * KP1;
        for (int g = t; g < KP1 / 4; g += 256) {
            float4 v;
            if (g < NFEAT / 4) v = src[g];
            else { v.x = 0.f; v.y = 0.f; v.z = 0.f; v.w = 0.f; }
            ushort4 o;
            o.x = f2b(v.x); o.y = f2b(v.y); o.z = f2b(v.z); o.w = f2b(v.w);
            *(ushort4*)(dst + g * 4) = o;
        }
    } else if (b < N_ATOMS + 352) {
        int bb = b - N_ATOMS;
        int p = bb / 88;
        int f0 = (bb % 88) * 32;
        #pragma unroll 4
        for (int i = 0; i < 32; ++i) {
            int f = f0 + i;
            float v = (f < NFEAT) ? W1[((size_t)p * NFEAT + f) * 256 + t] : 0.f;
            tile[i][t] = f2b(v);
        }
        __syncthreads();
        unsigned short* drow = B1t + (size_t)(p * 256 + t) * KP1 + f0;
        #pragma unroll
        for (int i = 0; i < 32; i += 4) {
            ushort4 o;
            o.x = tile[i][t]; o.y = tile[i + 1][t]; o.z = tile[i + 2][t]; o.w = tile[i + 3][t];
            *(ushort4*)(drow + i) = o;
        }
    } else {
        int bb = b - N_ATOMS - 352;   // 0..143
        if (bb < 64) {
            const float* W = (bb < 32) ? W2 : W3;
            unsigned short* Bt = (bb < 32) ? B2t : B3t;
            int b2 = bb & 31;
            int p = b2 >> 3;
            int f0 = (b2 & 7) * 32;
            #pragma unroll 4
            for (int i = 0; i < 32; ++i) {
                int f = f0 + i;
                tile[i][t] = f2b(W[((size_t)p * 256 + f) * 256 + t]);
            }
            __syncthreads();
            unsigned short* drow = Bt + (size_t)(p * 256 + t) * 256 + f0;
            #pragma unroll
            for (int i = 0; i < 32; i += 4) {
                ushort4 o;
                o.x = tile[i][t]; o.y = tile[i + 1][t]; o.z = tile[i + 2][t]; o.w = tile[i + 3][t];
                *(ushort4*)(drow + i) = o;
            }
        } else if (bb < 143) {
            int n = (bb - 64) * 256 + t;
            if (n < N_ATOMS) {
                int s = spec[n];
                float4 v = *(const float4*)(Wc + s * 4);
                *(float4*)(pw + n * 4) = v;
            }
        } else {
            for (int i = t; i < SS; i += 256) out[i] = 0.f;
        }
    }
}

// ---------------- Layer-1: 128x128 tile, 8 waves (4M x 2N), BK=64 ----------------
// R9: SINGLE-BARRIER K-step (was 2 barriers). Hazard re-derivation: per step t
//   frag-read(CB) -> lgkmcnt(0) -> MFMA -> vmcnt(0) -> s_barrier -> STAGE(CB<-t+2)
// (1) CB-overwrite safety: stage follows the barrier; every wave's ds_reads of
//     CB drained at its own lgkmcnt(0) before it reached the barrier.
// (2) cross-wave tile-(t+1) visibility: each wave drains its OWN gloads at
//     vmcnt(0) before the barrier -> after barrier all of CB^1 is valid.
// (3) depth: tile t+2 loads issued end-of-step t, consumed start-of-step t+2
//     (~1.8 steps >> 900cy HBM); the vmcnt(0) waits loads that already had a
//     full step -> nearly free. One barrier/step (44 vs 88).
// [R1..R8-proven base: dbuf 64KB -> 2 blocks/CU; (row&7) XOR chunk swizzle;
//  counted-prologue vmcnt(4)] LESSON (R4): BK<64 structurally bad. Do not revisit.
__global__ __launch_bounds__(512, 4) void gemm1_pipe(
    const unsigned short* __restrict__ A,
    const unsigned short* __restrict__ Bt,
    const float* __restrict__ pw,
    unsigned short* __restrict__ C)
{
    __shared__ __align__(16) unsigned short lds_a[2 * 8192];   // 32 KB
    __shared__ __align__(16) unsigned short lds_b[2 * 8192];   // 32 KB

    int bid = blockIdx.x;
    int swz = (bid & 7) * 158 + (bid >> 3);  // bijective XCD chunking (1264 = 8*158)
    int rowTile = swz >> 3;                  // 0..157
    int colTile = swz & 7;                   // 0..7
    int rowBase = rowTile * 128;
    int colBase = colTile * 128;
    int p = colTile >> 1;                    // pseudo-species of this 128-col slab

    int t0 = threadIdx.x;
    int wave = t0 >> 6;
    int lane = t0 & 63;
    int wm = wave >> 1;      // 0..3  (32-row slab)
    int wn = wave & 1;       // 0..1  (64-col slab)

    int rA = t0 >> 3;                         // 0..63
    int ckl = ((t0 & 7) ^ (rA & 7)) << 3;     // inverse-swizzled k elem offset
    const unsigned short* sa = A + (size_t)(rowBase + rA) * KP1 + ckl;
    const unsigned short* sb = Bt + (size_t)(colBase + rA) * KP1 + ckl;

    int ra0 = wm * 32 + (lane & 15);
    int rb0 = wn * 64 + (lane & 15);
    int xr = lane & 7;
    int c0 = lane >> 4;

    f32x4 acc[2][4];
    f32x4 z4 = {0.f, 0.f, 0.f, 0.f};
    #pragma unroll
    for (int i = 0; i < 2; ++i)
        #pragma unroll
        for (int j = 0; j < 4; ++j) acc[i][j] = z4;

#define STAGE1(SB) do { \
    GLOAD16(sa,                     lds_a + (SB) * 8192 + t0 * 8); \
    GLOAD16(sa + (size_t)64 * KP1,  lds_a + (SB) * 8192 + 4096 + t0 * 8); \
    GLOAD16(sb,                     lds_b + (SB) * 8192 + t0 * 8); \
    GLOAD16(sb + (size_t)64 * KP1,  lds_b + (SB) * 8192 + 4096 + t0 * 8); \
    sa += 64; sb += 64; \
} while (0)

    // prologue: stage tiles 0 and 1; enter step 0 with tile-0 drained by all waves
    STAGE1(0);
    STAGE1(1);
    asm volatile("s_waitcnt vmcnt(4)" ::: "memory");   // own tile-0 loads drained
    __builtin_amdgcn_s_barrier();                      // all waves: tile 0 visible
    __builtin_amdgcn_sched_barrier(0);

// Single-barrier step on buffer CB (tile t, landed & visible).
// DOSTAGE: issue tile t+2 into CB after the barrier (t <= 41).
#define FSTEP(CB, DOSTAGE) do { \
    s16x8 af[2][2], bv[2][4]; \
    _Pragma("unroll") \
    for (int kk = 0; kk < 2; ++kk) { \
        int ch = ((((kk << 2) | c0) ^ xr) << 3); \
        _Pragma("unroll") \
        for (int fm = 0; fm < 2; ++fm) \
            af[kk][fm] = *(const s16x8*)&lds_a[(CB) * 8192 + (ra0 + fm * 16) * 64 + ch]; \
        _Pragma("unroll") \
        for (int fn = 0; fn < 4; ++fn) \
            bv[kk][fn] = *(const s16x8*)&lds_b[(CB) * 8192 + (rb0 + fn * 16) * 64 + ch]; \
    } \
    asm volatile("s_waitcnt lgkmcnt(0)" ::: "memory"); \
    __builtin_amdgcn_sched_barrier(0); \
    __builtin_amdgcn_s_setprio(1); \
    _Pragma("unroll") \
    for (int kk = 0; kk < 2; ++kk) \
        _Pragma("unroll") \
        for (int fm = 0; fm < 2; ++fm) \
            _Pragma("unroll") \
            for (int fn = 0; fn < 4; ++fn) \
                acc[fm][fn] = __builtin_amdgcn_mfma_f32_16x16x32_bf16( \
                    af[kk][fm], bv[kk][fn], acc[fm][fn], 0, 0, 0); \
    __builtin_amdgcn_s_setprio(0); \
    asm volatile("s_waitcnt vmcnt(0)" ::: "memory");   /* own tile-(t+1) loads */ \
    __builtin_amdgcn_s_barrier();                      /* t+1 visible; CB reads done */ \
    __builtin_amdgcn_sched_barrier(0); \
    if (DOSTAGE) { STAGE1(CB); }                       /* tile t+2 over CB */ \
} while (0)

// Final step: reads + MFMA only (nothing outstanding, no LDS reuse after).
#define LSTEP(CB) do { \
    s16x8 af[2][2], bv[2][4]; \
    _Pragma("unroll") \
    for (int kk = 0; kk < 2; ++kk) { \
        int ch = ((((kk << 2) | c0) ^ xr) << 3); \
        _Pragma("unroll") \
        for (int fm = 0; fm < 2; ++fm) \
            af[kk][fm] = *(const s16x8*)&lds_a[(CB) * 8192 + (ra0 + fm * 16) * 64 + ch]; \
        _Pragma("unroll") \
        for (int fn = 0; fn < 4; ++fn) \
            bv[kk][fn] = *(const s16x8*)&lds_b[(CB) * 8192 + (rb0 + fn * 16) * 64 + ch]; \
    } \
    asm volatile("s_waitcnt lgkmcnt(0)" ::: "memory"); \
    __builtin_amdgcn_sched_barrier(0); \
    _Pragma("unroll") \
    for (int kk = 0; kk < 2; ++kk) \
        _Pragma("unroll") \
        for (int fm = 0; fm < 2; ++fm) \
            _Pragma("unroll") \
            for (int fn = 0; fn < 4; ++fn) \
                acc[fm][fn] = __builtin_amdgcn_mfma_f32_16x16x32_bf16( \
                    af[kk][fm], bv[kk][fn], acc[fm][fn], 0, 0, 0); \
} while (0)

    // 44 tiles: steps 0..41 stage tiles 2..43 (21 pairs); step 42 no-stage
    // (its vmcnt+barrier publishes tile 43); step 43 reads+MFMA only.
    for (int it = 0; it < 21; ++it) {
        FSTEP(0, 1);
        FSTEP(1, 1);
    }
    FSTEP(0, 0);     // t=42: drains+publishes tile 43, stages nothing
    LSTEP(1);        // t=43
#undef FSTEP
#undef LSTEP
#undef STAGE1

    // epilogue: C/D map col=lane&15, row=(lane>>4)*4+j  [m89-verified]
    int rGrp = (lane >> 4) << 2;
    int cLane = lane & 15;
    #pragma unroll
    for (int fm = 0; fm < 2; ++fm) {
        int r0 = rowBase + wm * 32 + fm * 16 + rGrp;
        float pwv[4];
        #pragma unroll
        for (int j = 0; j < 4; ++j) pwv[j] = pw[(size_t)(r0 + j) * 4 + p];
        #pragma unroll
        for (int fn = 0; fn < 4; ++fn) {
            int c = colBase + wn * 64 + fn * 16 + cLane;
            f32x4 a = acc[fm][fn];
            #pragma unroll
            for (int j = 0; j < 4; ++j) {
                float x = a[j] * pwv[j];
                float s = x / (1.f + __expf(-x));
                C[(size_t)(r0 + j) * MCOLS + c] = f2b(s);
            }
        }
    }
}

// ---------------- Layer 2: 128x128 tile, 2x2 waves, BK=64 (block-diag) ----------
// [R1/R5/R8-proven]
template<int USE_PW>
__global__ __launch_bounds__(256, 2) void gemm_silu(
    const unsigned short* __restrict__ A, int lda,
    const unsigned short* __restrict__ Bt, int ldb,
    int K, int aOffPerP,
    const float* __restrict__ pw,
    unsigned short* __restrict__ C)
{
    __shared__ __align__(16) unsigned short lds_a[128 * 64];
    __shared__ __align__(16) unsigned short lds_b[128 * 64];

    int bid = blockIdx.x;
    int colTile = bid & 7;
    int rowTile = bid >> 3;
    int rowBase = rowTile * 128;
    int colBase = colTile * 128;
    int p = colBase >> 8;
    int aOff = p * aOffPerP;

    int t = threadIdx.x;
    int wave = t >> 6;
    int lane = t & 63;
    int wm = wave >> 1, wn = wave & 1;

    int trow = t >> 3;
    int kcol = (((t & 7) ^ (trow & 7)) << 3);
    const unsigned short* srcA = A + (size_t)(rowBase + trow) * lda + aOff + kcol;
    const unsigned short* srcB = Bt + (size_t)(colBase + trow) * ldb + kcol;

    f32x4 acc[4][4];
    f32x4 z4 = {0.f, 0.f, 0.f, 0.f};
    #pragma unroll
    for (int i = 0; i < 4; ++i)
        #pragma unroll
        for (int j = 0; j < 4; ++j) acc[i][j] = z4;

    int rb = wm * 64 + (lane & 15);
    int cb = wn * 64 + (lane & 15);
    int c0 = lane >> 4;
    int xr = lane & 7;

    int KT = K >> 6;
    for (int kt = 0; kt < KT; ++kt) {
        #pragma unroll
        for (int i = 0; i < 4; ++i) {
            GLOAD16(srcA + (size_t)i * 32 * lda, lds_a + i * 2048 + wave * 512);
            GLOAD16(srcB + (size_t)i * 32 * ldb, lds_b + i * 2048 + wave * 512);
        }
        srcA += 64; srcB += 64;
        __syncthreads();

        #pragma unroll
        for (int kk = 0; kk < 2; ++kk) {
            s16x8 af[4], bfr[4];
            int ch = (((kk << 2) | c0) ^ xr) << 3;
            #pragma unroll
            for (int fm = 0; fm < 4; ++fm)
                af[fm] = *(const s16x8*)&lds_a[(rb + fm * 16) * 64 + ch];
            #pragma unroll
            for (int fn = 0; fn < 4; ++fn)
                bfr[fn] = *(const s16x8*)&lds_b[(cb + fn * 16) * 64 + ch];
            #pragma unroll
            for (int fm = 0; fm < 4; ++fm)
                #pragma unroll
                for (int fn = 0; fn < 4; ++fn)
                    acc[fm][fn] = __builtin_amdgcn_mfma_f32_16x16x32_bf16(
                        af[fm], bfr[fn], acc[fm][fn], 0, 0, 0);
        }
        __syncthreads();
    }

    int rGrp = (lane >> 4) << 2;
    int cLane = lane & 15;
    #pragma unroll
    for (int fm = 0; fm < 4; ++fm) {
        int r0 = rowBase + wm * 64 + fm * 16 + rGrp;
        float pwv[4];
        if (USE_PW) {
            #pragma unroll
            for (int j = 0; j < 4; ++j) pwv[j] = pw[(size_t)(r0 + j) * 4 + p];
        }
        #pragma unroll
        for (int fn = 0; fn < 4; ++fn) {
            int c = colBase + wn * 64 + fn * 16 + cLane;
            f32x4 a = acc[fm][fn];
            #pragma unroll
            for (int j = 0; j < 4; ++j) {
                float x = a[j];
                if (USE_PW) x *= pwv[j];
                float s = x / (1.f + __expf(-x));
                C[(size_t)(r0 + j) * MCOLS + c] = f2b(s);
            }
        }
    }
}

// ---------------- Layer 3 + 4 fused: GEMM + silu + dot(W4) -> row partials ------
// [R8-proven] epilogue computes the W4 dot in-register; cLane==0 writes
// ep[row][colTile*2+wn] (1.3MB) instead of h3 (41MB write + 41MB re-read).
__global__ __launch_bounds__(256, 2) void gemm_dot3(
    const unsigned short* __restrict__ A,    // h2, lda 1024, block-diag p*256
    const unsigned short* __restrict__ Bt,   // B3t, ldb 256
    const float* __restrict__ W4,            // flat [1024]
    float* __restrict__ ep)                  // [NPAD][16] partials
{
    __shared__ __align__(16) unsigned short lds_a[128 * 64];
    __shared__ __align__(16) unsigned short lds_b[128 * 64];

    int bid = blockIdx.x;
    int colTile = bid & 7;
    int rowTile = bid >> 3;
    int rowBase = rowTile * 128;
    int colBase = colTile * 128;
    int p = colBase >> 8;
    int aOff = p * 256;

    int t = threadIdx.x;
    int wave = t >> 6;
    int lane = t & 63;
    int wm = wave >> 1, wn = wave & 1;

    int trow = t >> 3;
    int kcol = (((t & 7) ^ (trow & 7)) << 3);
    const unsigned short* srcA = A + (size_t)(rowBase + trow) * 1024 + aOff + kcol;
    const unsigned short* srcB = Bt + (size_t)(colBase + trow) * 256 + kcol;

    f32x4 acc[4][4];
    f32x4 z4 = {0.f, 0.f, 0.f, 0.f};
    #pragma unroll
    for (int i = 0; i < 4; ++i)
        #pragma unroll
        for (int j = 0; j < 4; ++j) acc[i][j] = z4;

    int rb = wm * 64 + (lane & 15);
    int cb = wn * 64 + (lane & 15);
    int c0 = lane >> 4;
    int xr = lane & 7;

    for (int kt = 0; kt < 4; ++kt) {
        #pragma unroll
        for (int i = 0; i < 4; ++i) {
            GLOAD16(srcA + (size_t)i * 32 * 1024, lds_a + i * 2048 + wave * 512);
            GLOAD16(srcB + (size_t)i * 32 * 256,  lds_b + i * 2048 + wave * 512);
        }
        srcA += 64; srcB += 64;
        __syncthreads();

        #pragma unroll
        for (int kk = 0; kk < 2; ++kk) {
            s16x8 af[4], bfr[4];
            int ch = (((kk << 2) | c0) ^ xr) << 3;
            #pragma unroll
            for (int fm = 0; fm < 4; ++fm)
                af[fm] = *(const s16x8*)&lds_a[(rb + fm * 16) * 64 + ch];
            #pragma unroll
            for (int fn = 0; fn < 4; ++fn)
                bfr[fn] = *(const s16x8*)&lds_b[(cb + fn * 16) * 64 + ch];
            #pragma unroll
            for (int fm = 0; fm < 4; ++fm)
                #pragma unroll
                for (int fn = 0; fn < 4; ++fn)
                    acc[fm][fn] = __builtin_amdgcn_mfma_f32_16x16x32_bf16(
                        af[fm], bfr[fn], acc[fm][fn], 0, 0, 0);
        }
        __syncthreads();
    }

    int rGrp = (lane >> 4) << 2;
    int cLane = lane & 15;
    float w4v[4];
    #pragma unroll
    for (int fn = 0; fn < 4; ++fn)
        w4v[fn] = W4[colBase + wn * 64 + fn * 16 + cLane];
    #pragma unroll
    for (int fm = 0; fm < 4; ++fm) {
        #pragma unroll
        for (int j = 0; j < 4; ++j) {
            float s = 0.f;
            #pragma unroll
            for (int fn = 0; fn < 4; ++fn) {
                float x = acc[fm][fn][j];
                s += (x / (1.f + __expf(-x))) * w4v[fn];
            }
            s += __shfl_xor(s, 1);
            s += __shfl_xor(s, 2);
            s += __shfl_xor(s, 4);
            s += __shfl_xor(s, 8);
            if (cLane == 0) {
                int row = rowBase + wm * 64 + fm * 16 + rGrp + j;
                ep[(size_t)row * 16 + colTile * 2 + wn] = s;
            }
        }
    }
}

// sum the 16 per-column-slab partials; one atomicAdd per atom
__global__ void finalize2(const float* __restrict__ ep, const int* __restrict__ sidx,
                          float* __restrict__ out) {
    int n = blockIdx.x * 256 + threadIdx.x;
    if (n >= N_ATOMS) return;
    const float4* v = (const float4*)(ep + (size_t)n * 16);
    float4 a = v[0], b = v[1], c = v[2], d = v[3];
    float s = (a.x + a.y + a.z + a.w) + (b.x + b.y + b.z + b.w)
            + (c.x + c.y + c.z + c.w) + (d.x + d.y + d.z + d.w);
    atomicAdd(out + sidx[n], s * 0.0125f);   // (1/sqrt(4))/40
}

extern "C" void kernel_launch(void* const* d_in, const int* in_sizes, int n_in,
                              void* d_out, int out_size, void* d_ws, size_t ws_size,
                              hipStream_t stream) {
    const float* features = (const float*)d_in[0];
    const float* W_comb   = (const float*)d_in[1];
    const float* W1       = (const float*)d_in[2];
    const float* W2       = (const float*)d_in[3];
    const float* W3       = (const float*)d_in[4];
    const float* W4       = (const float*)d_in[5];
    const int*   species  = (const int*)d_in[6];
    const int*   sidx     = (const int*)d_in[7];
    float* out = (float*)d_out;

    char* ws = (char*)d_ws;
    size_t off = 0;
    auto carve = [&](size_t bytes) {
        char* r = ws + off;
        off += (bytes + 255) & ~(size_t)255;
        return r;
    };
    unsigned short* feat = (unsigned short*)carve((size_t)NPAD * KP1 * 2);   // 113.9 MB
    unsigned short* B1t  = (unsigned short*)carve((size_t)1024 * KP1 * 2 + 4096); // 5.8 MB
    unsigned short* B2t  = (unsigned short*)carve((size_t)1024 * 256 * 2);
    unsigned short* B3t  = (unsigned short*)carve((size_t)1024 * 256 * 2);
    float*          pw   = (float*)carve((size_t)NPAD * 4 * 4);
    unsigned short* h1   = (unsigned short*)carve((size_t)NPAD * 1024 * 2);  // 41.4 MB
    float*          ep   = (float*)carve((size_t)NPAD * 16 * 4);             // 1.3 MB
    carve(4096);                                                             // slack
    unsigned short* h2   = feat;  // feat dead after gemm1; reuse as h2

    // all prep in one launch: conv_feat | pack W1 | pack W2/W3 | pw | zero-out
    prep_all<<<N_ATOMS + 352 + 144, 256, 0, stream>>>(
        features, feat, W1, B1t, W2, W3, B2t, B3t, W_comb, species, pw, out);

    // layer 1: [NPAD x 2816] * [2816 x 1024] -> h1 (pw-scaled silu), single-barrier pipe
    gemm1_pipe<<<158 * 8, 512, 0, stream>>>(feat, B1t, pw, h1);
    // layer 2: block-diagonal, A col offset p*256
    gemm_silu<0><<<158 * 8, 256, 0, stream>>>(h1, 1024, B2t, 256, 256, 256, nullptr, h2);
    // layer 3 + 4 fused: GEMM + silu + W4-dot -> per-row partials (no h3)
    gemm_dot3<<<158 * 8, 256, 0, stream>>>(h2, B3t, W4, ep);
    // sum partials + segment scatter
    finalize2<<<(N_ATOMS + 255) / 256, 256, 0, stream>>>(ep, sidx, out);
}

// Round 10
// 264.439 us; speedup vs baseline: 1.0273x; 1.0273x over previous
//
#include <hip/hip_runtime.h>
#include <hip/hip_bf16.h>
#include <stdint.h>

#define N_ATOMS 20000
#define NFEAT   2784
#define KP1     2816      // 44 * 64, K-pad for layer 1 (2784 real + 32 zero)
#define SS      500
#define NPAD    20224     // 158 * 128
#define MCOLS   1024      // P*H

typedef __attribute__((ext_vector_type(8))) short s16x8;
typedef __attribute__((ext_vector_type(4))) float f32x4;

static __device__ __forceinline__ unsigned short f2b(float f) {
    __hip_bfloat16 h = __float2bfloat16(f);
    return __builtin_bit_cast(unsigned short, h);
}
static __device__ __forceinline__ float b2f(unsigned short u) {
    unsigned int x = ((unsigned int)u) << 16;
    return __builtin_bit_cast(float, x);
}

#define GLOAD16(g, l) __builtin_amdgcn_global_load_lds( \
    (const __attribute__((address_space(1))) void*)(g), \
    (__attribute__((address_space(3))) void*)(l), 16, 0, 0)

// ---------------- Fused prep: conv_feat + pack_w(W1) + W2/W3/pw/zero ------------
// [R8-proven] blocks [0,20000): feat fp32->bf16; [20000,20352): pack W1;
// [20352,20496): pack W2 | pack W3 | make_pw | zero.
// LESSON (R2/R6/R7): fusing fp32->bf16 INTO gemm1's A-path failed 3 structural
// ways (latency-on-critical-path; regset spill 400MB; residual spill 80MB).
// Keep conversion as a separate BW-bound pass. Do not revisit.
__global__ void prep_all(const float* __restrict__ F, unsigned short* __restrict__ feat,
                         const float* __restrict__ W1, unsigned short* __restrict__ B1t,
                         const float* __restrict__ W2, const float* __restrict__ W3,
                         unsigned short* __restrict__ B2t, unsigned short* __restrict__ B3t,
                         const float* __restrict__ Wc, const int* __restrict__ spec,
                         float* __restrict__ pw, float* __restrict__ out) {
    __shared__ unsigned short tile[32][256];
    int b = blockIdx.x;
    int t = threadIdx.x;
    if (b < N_ATOMS) {
        const float4* src = (const float4*)(F + (size_t)b * NFEAT);
        unsigned short* dst = feat + (size_t)b * KP1;
        for (int g = t; g < KP1 / 4; g += 256) {
            float4 v;
            if (g < NFEAT / 4) v = src[g];
            else { v.x = 0.f; v.y = 0.f; v.z = 0.f; v.w = 0.f; }
            ushort4 o;
            o.x = f2b(v.x); o.y = f2b(v.y); o.z = f2b(v.z); o.w = f2b(v.w);
            *(ushort4*)(dst + g * 4) = o;
        }
    } else if (b < N_ATOMS + 352) {
        int bb = b - N_ATOMS;
        int p = bb / 88;
        int f0 = (bb % 88) * 32;
        #pragma unroll 4
        for (int i = 0; i < 32; ++i) {
            int f = f0 + i;
            float v = (f < NFEAT) ? W1[((size_t)p * NFEAT + f) * 256 + t] : 0.f;
            tile[i][t] = f2b(v);
        }
        __syncthreads();
        unsigned short* drow = B1t + (size_t)(p * 256 + t) * KP1 + f0;
        #pragma unroll
        for (int i = 0; i < 32; i += 4) {
            ushort4 o;
            o.x = tile[i][t]; o.y = tile[i + 1][t]; o.z = tile[i + 2][t]; o.w = tile[i + 3][t];
            *(ushort4*)(drow + i) = o;
        }
    } else {
        int bb = b - N_ATOMS - 352;   // 0..143
        if (bb < 64) {
            const float* W = (bb < 32) ? W2 : W3;
            unsigned short* Bt = (bb < 32) ? B2t : B3t;
            int b2 = bb & 31;
            int p = b2 >> 3;
            int f0 = (b2 & 7) * 32;
            #pragma unroll 4
            for (int i = 0; i < 32; ++i) {
                int f = f0 + i;
                tile[i][t] = f2b(W[((size_t)p * 256 + f) * 256 + t]);
            }
            __syncthreads();
            unsigned short* drow = Bt + (size_t)(p * 256 + t) * 256 + f0;
            #pragma unroll
            for (int i = 0; i < 32; i += 4) {
                ushort4 o;
                o.x = tile[i][t]; o.y = tile[i + 1][t]; o.z = tile[i + 2][t]; o.w = tile[i + 3][t];
                *(ushort4*)(drow + i) = o;
            }
        } else if (bb < 143) {
            int n = (bb - 64) * 256 + t;
            if (n < N_ATOMS) {
                int s = spec[n];
                float4 v = *(const float4*)(Wc + s * 4);
                *(float4*)(pw + n * 4) = v;
            }
        } else {
            for (int i = t; i < SS; i += 256) out[i] = 0.f;
        }
    }
}

// ---------------- Layer-1: 128x128 tile, 8 waves (4M x 2N), BK=64 ----------------
// [R8-proven, BYTE-IDENTICAL restore: 147-150 us, MfmaUtil ~34, FETCH ~150MB,
//  WRITE ~40MB, conflicts 0] Two-barrier K-step with COUNTED vmcnt(4):
//   frag-read(CB) -> lgkmcnt(0) -> barrier#1 (read-done) -> STAGE(CB<-t+2)
//   -> MFMA -> vmcnt(4) [waits tile t+1, leaves t+2 in flight] -> barrier#2.
// LESSON (R9): single-barrier variant forces vmcnt(0) drain per step (stage-
// after-barrier leaves no older loads to count past) -> pipeline flush, -15%
// (148->171us, MfmaUtil 34->28). Barrier#1 is what ENABLES the counted wait
// at barrier#2. Do not revisit.
// LESSON (R4): BK<64 structurally bad (half-line fetches, L2 thrash, degenerate
// swizzle -> 4-way conflicts). Do not revisit.
__global__ __launch_bounds__(512, 4) void gemm1_pipe(
    const unsigned short* __restrict__ A,
    const unsigned short* __restrict__ Bt,
    const float* __restrict__ pw,
    unsigned short* __restrict__ C)
{
    __shared__ __align__(16) unsigned short lds_a[2 * 8192];   // 32 KB
    __shared__ __align__(16) unsigned short lds_b[2 * 8192];   // 32 KB

    int bid = blockIdx.x;
    int swz = (bid & 7) * 158 + (bid >> 3);  // bijective XCD chunking (1264 = 8*158)
    int rowTile = swz >> 3;                  // 0..157
    int colTile = swz & 7;                   // 0..7
    int rowBase = rowTile * 128;
    int colBase = colTile * 128;
    int p = colTile >> 1;                    // pseudo-species of this 128-col slab

    int t0 = threadIdx.x;
    int wave = t0 >> 6;
    int lane = t0 & 63;
    int wm = wave >> 1;      // 0..3  (32-row slab)
    int wn = wave & 1;       // 0..1  (64-col slab)

    int rA = t0 >> 3;                         // 0..63
    int ckl = ((t0 & 7) ^ (rA & 7)) << 3;     // inverse-swizzled k elem offset
    const unsigned short* sa = A + (size_t)(rowBase + rA) * KP1 + ckl;
    const unsigned short* sb = Bt + (size_t)(colBase + rA) * KP1 + ckl;

    int ra0 = wm * 32 + (lane & 15);
    int rb0 = wn * 64 + (lane & 15);
    int xr = lane & 7;
    int c0 = lane >> 4;

    f32x4 acc[2][4];
    f32x4 z4 = {0.f, 0.f, 0.f, 0.f};
    #pragma unroll
    for (int i = 0; i < 2; ++i)
        #pragma unroll
        for (int j = 0; j < 4; ++j) acc[i][j] = z4;

#define STAGE1(SB) do { \
    GLOAD16(sa,                     lds_a + (SB) * 8192 + t0 * 8); \
    GLOAD16(sa + (size_t)64 * KP1,  lds_a + (SB) * 8192 + 4096 + t0 * 8); \
    GLOAD16(sb,                     lds_b + (SB) * 8192 + t0 * 8); \
    GLOAD16(sb + (size_t)64 * KP1,  lds_b + (SB) * 8192 + 4096 + t0 * 8); \
    sa += 64; sb += 64; \
} while (0)

    STAGE1(0);
    STAGE1(1);
    asm volatile("s_waitcnt vmcnt(4)" ::: "memory");   // tile 0 landed
    __builtin_amdgcn_s_barrier();
    __builtin_amdgcn_sched_barrier(0);

#define FSTEP(CB) do { \
    s16x8 af[2][2], bv[2][4]; \
    _Pragma("unroll") \
    for (int kk = 0; kk < 2; ++kk) { \
        int ch = ((((kk << 2) | c0) ^ xr) << 3); \
        _Pragma("unroll") \
        for (int fm = 0; fm < 2; ++fm) \
            af[kk][fm] = *(const s16x8*)&lds_a[(CB) * 8192 + (ra0 + fm * 16) * 64 + ch]; \
        _Pragma("unroll") \
        for (int fn = 0; fn < 4; ++fn) \
            bv[kk][fn] = *(const s16x8*)&lds_b[(CB) * 8192 + (rb0 + fn * 16) * 64 + ch]; \
    } \
    asm volatile("s_waitcnt lgkmcnt(0)" ::: "memory"); \
    __builtin_amdgcn_sched_barrier(0); \
    __builtin_amdgcn_s_barrier();            /* all waves done reading CB */ \
    __builtin_amdgcn_sched_barrier(0); \
    STAGE1(CB);                              /* tile t+2 over CB */ \
    __builtin_amdgcn_s_setprio(1); \
    _Pragma("unroll") \
    for (int kk = 0; kk < 2; ++kk) \
        _Pragma("unroll") \
        for (int fm = 0; fm < 2; ++fm) \
            _Pragma("unroll") \
            for (int fn = 0; fn < 4; ++fn) \
                acc[fm][fn] = __builtin_amdgcn_mfma_f32_16x16x32_bf16( \
                    af[kk][fm], bv[kk][fn], acc[fm][fn], 0, 0, 0); \
    __builtin_amdgcn_s_setprio(0); \
    asm volatile("s_waitcnt vmcnt(4)" ::: "memory");   /* tile t+1 landed */ \
    __builtin_amdgcn_s_barrier(); \
    __builtin_amdgcn_sched_barrier(0); \
} while (0)

#define TSTEP(CB, DRAIN) do { \
    s16x8 af[2][2], bv[2][4]; \
    _Pragma("unroll") \
    for (int kk = 0; kk < 2; ++kk) { \
        int ch = ((((kk << 2) | c0) ^ xr) << 3); \
        _Pragma("unroll") \
        for (int fm = 0; fm < 2; ++fm) \
            af[kk][fm] = *(const s16x8*)&lds_a[(CB) * 8192 + (ra0 + fm * 16) * 64 + ch]; \
        _Pragma("unroll") \
        for (int fn = 0; fn < 4; ++fn) \
            bv[kk][fn] = *(const s16x8*)&lds_b[(CB) * 8192 + (rb0 + fn * 16) * 64 + ch]; \
    } \
    _Pragma("unroll") \
    for (int kk = 0; kk < 2; ++kk) \
        _Pragma("unroll") \
        for (int fm = 0; fm < 2; ++fm) \
            _Pragma("unroll") \
            for (int fn = 0; fn < 4; ++fn) \
                acc[fm][fn] = __builtin_amdgcn_mfma_f32_16x16x32_bf16( \
                    af[kk][fm], bv[kk][fn], acc[fm][fn], 0, 0, 0); \
    if (DRAIN) { \
        asm volatile("s_waitcnt vmcnt(0)" ::: "memory"); \
        __builtin_amdgcn_s_barrier(); \
        __builtin_amdgcn_sched_barrier(0); \
    } \
} while (0)

    // 44 tiles: 42 full steps (stage tiles 2..43) = 21 pairs, then 2 tail steps
    for (int it = 0; it < 21; ++it) {
        FSTEP(0);
        FSTEP(1);
    }
    TSTEP(0, 1);     // t=42, then drain tile 43
    TSTEP(1, 0);     // t=43
#undef FSTEP
#undef TSTEP
#undef STAGE1

    // epilogue: C/D map col=lane&15, row=(lane>>4)*4+j  [m89-verified]
    int rGrp = (lane >> 4) << 2;
    int cLane = lane & 15;
    #pragma unroll
    for (int fm = 0; fm < 2; ++fm) {
        int r0 = rowBase + wm * 32 + fm * 16 + rGrp;
        float pwv[4];
        #pragma unroll
        for (int j = 0; j < 4; ++j) pwv[j] = pw[(size_t)(r0 + j) * 4 + p];
        #pragma unroll
        for (int fn = 0; fn < 4; ++fn) {
            int c = colBase + wn * 64 + fn * 16 + cLane;
            f32x4 a = acc[fm][fn];
            #pragma unroll
            for (int j = 0; j < 4; ++j) {
                float x = a[j] * pwv[j];
                float s = x / (1.f + __expf(-x));
                C[(size_t)(r0 + j) * MCOLS + c] = f2b(s);
            }
        }
    }
}

// ---------------- Layer 2: 128x128 tile, 2x2 waves, BK=64 (block-diag) ----------
// [R1/R5/R8-proven]
template<int USE_PW>
__global__ __launch_bounds__(256, 2) void gemm_silu(
    const unsigned short* __restrict__ A, int lda,
    const unsigned short* __restrict__ Bt, int ldb,
    int K, int aOffPerP,
    const float* __restrict__ pw,
    unsigned short* __restrict__ C)
{
    __shared__ __align__(16) unsigned short lds_a[128 * 64];
    __shared__ __align__(16) unsigned short lds_b[128 * 64];

    int bid = blockIdx.x;
    int colTile = bid & 7;
    int rowTile = bid >> 3;
    int rowBase = rowTile * 128;
    int colBase = colTile * 128;
    int p = colBase >> 8;
    int aOff = p * aOffPerP;

    int t = threadIdx.x;
    int wave = t >> 6;
    int lane = t & 63;
    int wm = wave >> 1, wn = wave & 1;

    int trow = t >> 3;
    int kcol = (((t & 7) ^ (trow & 7)) << 3);
    const unsigned short* srcA = A + (size_t)(rowBase + trow) * lda + aOff + kcol;
    const unsigned short* srcB = Bt + (size_t)(colBase + trow) * ldb + kcol;

    f32x4 acc[4][4];
    f32x4 z4 = {0.f, 0.f, 0.f, 0.f};
    #pragma unroll
    for (int i = 0; i < 4; ++i)
        #pragma unroll
        for (int j = 0; j < 4; ++j) acc[i][j] = z4;

    int rb = wm * 64 + (lane & 15);
    int cb = wn * 64 + (lane & 15);
    int c0 = lane >> 4;
    int xr = lane & 7;

    int KT = K >> 6;
    for (int kt = 0; kt < KT; ++kt) {
        #pragma unroll
        for (int i = 0; i < 4; ++i) {
            GLOAD16(srcA + (size_t)i * 32 * lda, lds_a + i * 2048 + wave * 512);
            GLOAD16(srcB + (size_t)i * 32 * ldb, lds_b + i * 2048 + wave * 512);
        }
        srcA += 64; srcB += 64;
        __syncthreads();

        #pragma unroll
        for (int kk = 0; kk < 2; ++kk) {
            s16x8 af[4], bfr[4];
            int ch = (((kk << 2) | c0) ^ xr) << 3;
            #pragma unroll
            for (int fm = 0; fm < 4; ++fm)
                af[fm] = *(const s16x8*)&lds_a[(rb + fm * 16) * 64 + ch];
            #pragma unroll
            for (int fn = 0; fn < 4; ++fn)
                bfr[fn] = *(const s16x8*)&lds_b[(cb + fn * 16) * 64 + ch];
            #pragma unroll
            for (int fm = 0; fm < 4; ++fm)
                #pragma unroll
                for (int fn = 0; fn < 4; ++fn)
                    acc[fm][fn] = __builtin_amdgcn_mfma_f32_16x16x32_bf16(
                        af[fm], bfr[fn], acc[fm][fn], 0, 0, 0);
        }
        __syncthreads();
    }

    int rGrp = (lane >> 4) << 2;
    int cLane = lane & 15;
    #pragma unroll
    for (int fm = 0; fm < 4; ++fm) {
        int r0 = rowBase + wm * 64 + fm * 16 + rGrp;
        float pwv[4];
        if (USE_PW) {
            #pragma unroll
            for (int j = 0; j < 4; ++j) pwv[j] = pw[(size_t)(r0 + j) * 4 + p];
        }
        #pragma unroll
        for (int fn = 0; fn < 4; ++fn) {
            int c = colBase + wn * 64 + fn * 16 + cLane;
            f32x4 a = acc[fm][fn];
            #pragma unroll
            for (int j = 0; j < 4; ++j) {
                float x = a[j];
                if (USE_PW) x *= pwv[j];
                float s = x / (1.f + __expf(-x));
                C[(size_t)(r0 + j) * MCOLS + c] = f2b(s);
            }
        }
    }
}

// ---------------- Layer 3 + 4 fused: GEMM + silu + dot(W4) -> row partials ------
// [R8-proven] epilogue computes the W4 dot in-register; cLane==0 writes
// ep[row][colTile*2+wn] (1.3MB) instead of h3 (41MB write + 41MB re-read).
__global__ __launch_bounds__(256, 2) void gemm_dot3(
    const unsigned short* __restrict__ A,    // h2, lda 1024, block-diag p*256
    const unsigned short* __restrict__ Bt,   // B3t, ldb 256
    const float* __restrict__ W4,            // flat [1024]
    float* __restrict__ ep)                  // [NPAD][16] partials
{
    __shared__ __align__(16) unsigned short lds_a[128 * 64];
    __shared__ __align__(16) unsigned short lds_b[128 * 64];

    int bid = blockIdx.x;
    int colTile = bid & 7;
    int rowTile = bid >> 3;
    int rowBase = rowTile * 128;
    int colBase = colTile * 128;
    int p = colBase >> 8;
    int aOff = p * 256;

    int t = threadIdx.x;
    int wave = t >> 6;
    int lane = t & 63;
    int wm = wave >> 1, wn = wave & 1;

    int trow = t >> 3;
    int kcol = (((t & 7) ^ (trow & 7)) << 3);
    const unsigned short* srcA = A + (size_t)(rowBase + trow) * 1024 + aOff + kcol;
    const unsigned short* srcB = Bt + (size_t)(colBase + trow) * 256 + kcol;

    f32x4 acc[4][4];
    f32x4 z4 = {0.f, 0.f, 0.f, 0.f};
    #pragma unroll
    for (int i = 0; i < 4; ++i)
        #pragma unroll
        for (int j = 0; j < 4; ++j) acc[i][j] = z4;

    int rb = wm * 64 + (lane & 15);
    int cb = wn * 64 + (lane & 15);
    int c0 = lane >> 4;
    int xr = lane & 7;

    for (int kt = 0; kt < 4; ++kt) {
        #pragma unroll
        for (int i = 0; i < 4; ++i) {
            GLOAD16(srcA + (size_t)i * 32 * 1024, lds_a + i * 2048 + wave * 512);
            GLOAD16(srcB + (size_t)i * 32 * 256,  lds_b + i * 2048 + wave * 512);
        }
        srcA += 64; srcB += 64;
        __syncthreads();

        #pragma unroll
        for (int kk = 0; kk < 2; ++kk) {
            s16x8 af[4], bfr[4];
            int ch = (((kk << 2) | c0) ^ xr) << 3;
            #pragma unroll
            for (int fm = 0; fm < 4; ++fm)
                af[fm] = *(const s16x8*)&lds_a[(rb + fm * 16) * 64 + ch];
            #pragma unroll
            for (int fn = 0; fn < 4; ++fn)
                bfr[fn] = *(const s16x8*)&lds_b[(cb + fn * 16) * 64 + ch];
            #pragma unroll
            for (int fm = 0; fm < 4; ++fm)
                #pragma unroll
                for (int fn = 0; fn < 4; ++fn)
                    acc[fm][fn] = __builtin_amdgcn_mfma_f32_16x16x32_bf16(
                        af[fm], bfr[fn], acc[fm][fn], 0, 0, 0);
        }
        __syncthreads();
    }

    int rGrp = (lane >> 4) << 2;
    int cLane = lane & 15;
    float w4v[4];
    #pragma unroll
    for (int fn = 0; fn < 4; ++fn)
        w4v[fn] = W4[colBase + wn * 64 + fn * 16 + cLane];
    #pragma unroll
    for (int fm = 0; fm < 4; ++fm) {
        #pragma unroll
        for (int j = 0; j < 4; ++j) {
            float s = 0.f;
            #pragma unroll
            for (int fn = 0; fn < 4; ++fn) {
                float x = acc[fm][fn][j];
                s += (x / (1.f + __expf(-x))) * w4v[fn];
            }
            s += __shfl_xor(s, 1);
            s += __shfl_xor(s, 2);
            s += __shfl_xor(s, 4);
            s += __shfl_xor(s, 8);
            if (cLane == 0) {
                int row = rowBase + wm * 64 + fm * 16 + rGrp + j;
                ep[(size_t)row * 16 + colTile * 2 + wn] = s;
            }
        }
    }
}

// sum the 16 per-column-slab partials; one atomicAdd per atom
__global__ void finalize2(const float* __restrict__ ep, const int* __restrict__ sidx,
                          float* __restrict__ out) {
    int n = blockIdx.x * 256 + threadIdx.x;
    if (n >= N_ATOMS) return;
    const float4* v = (const float4*)(ep + (size_t)n * 16);
    float4 a = v[0], b = v[1], c = v[2], d = v[3];
    float s = (a.x + a.y + a.z + a.w) + (b.x + b.y + b.z + b.w)
            + (c.x + c.y + c.z + c.w) + (d.x + d.y + d.z + d.w);
    atomicAdd(out + sidx[n], s * 0.0125f);   // (1/sqrt(4))/40
}

extern "C" void kernel_launch(void* const* d_in, const int* in_sizes, int n_in,
                              void* d_out, int out_size, void* d_ws, size_t ws_size,
                              hipStream_t stream) {
    const float* features = (const float*)d_in[0];
    const float* W_comb   = (const float*)d_in[1];
    const float* W1       = (const float*)d_in[2];
    const float* W2       = (const float*)d_in[3];
    const float* W3       = (const float*)d_in[4];
    const float* W4       = (const float*)d_in[5];
    const int*   species  = (const int*)d_in[6];
    const int*   sidx     = (const int*)d_in[7];
    float* out = (float*)d_out;

    char* ws = (char*)d_ws;
    size_t off = 0;
    auto carve = [&](size_t bytes) {
        char* r = ws + off;
        off += (bytes + 255) & ~(size_t)255;
        return r;
    };
    unsigned short* feat = (unsigned short*)carve((size_t)NPAD * KP1 * 2);   // 113.9 MB
    unsigned short* B1t  = (unsigned short*)carve((size_t)1024 * KP1 * 2 + 4096); // 5.8 MB
    unsigned short* B2t  = (unsigned short*)carve((size_t)1024 * 256 * 2);
    unsigned short* B3t  = (unsigned short*)carve((size_t)1024 * 256 * 2);
    float*          pw   = (float*)carve((size_t)NPAD * 4 * 4);
    unsigned short* h1   = (unsigned short*)carve((size_t)NPAD * 1024 * 2);  // 41.4 MB
    float*          ep   = (float*)carve((size_t)NPAD * 16 * 4);             // 1.3 MB
    carve(4096);                                                             // slack
    unsigned short* h2   = feat;  // feat dead after gemm1; reuse as h2

    // all prep in one launch: conv_feat | pack W1 | pack W2/W3 | pw | zero-out
    prep_all<<<N_ATOMS + 352 + 144, 256, 0, stream>>>(
        features, feat, W1, B1t, W2, W3, B2t, B3t, W_comb, species, pw, out);

    // layer 1: [NPAD x 2816] * [2816 x 1024] -> h1 (pw-scaled silu), 2-barrier pipe
    gemm1_pipe<<<158 * 8, 512, 0, stream>>>(feat, B1t, pw, h1);
    // layer 2: block-diagonal, A col offset p*256
    gemm_silu<0><<<158 * 8, 256, 0, stream>>>(h1, 1024, B2t, 256, 256, 256, nullptr, h2);
    // layer 3 + 4 fused: GEMM + silu + W4-dot -> per-row partials (no h3)
    gemm_dot3<<<158 * 8, 256, 0, stream>>>(h2, B3t, W4, ep);
    // sum partials + segment scatter
    finalize2<<<(N_ATOMS + 255) / 256, 256, 0, stream>>>(ep, sidx, out);
}